// Round 3
// baseline (154.760 us; speedup 1.0000x reference)
//
#include <hip/hip_runtime.h>

#define NB 32768
#define NF 256
#define H1 16
#define H2 8
#define FG 16                    // features per block
#define RJ 8                     // rows per lane
#define ROWS_PER_BLOCK (16 * RJ) // 128 rows per block

__device__ __forceinline__ float elu_f(float v) {
    return v > 0.0f ? v : (__expf(v) - 1.0f);
}

// Init: y = bias (atomic accumulation target), w_out = softplus(theta).
__global__ __launch_bounds__(256)
void nul_init(const float* __restrict__ theta, const float* __restrict__ bias,
              float* __restrict__ y_out, float* __restrict__ w_out) {
    const int t = blockIdx.x * 256 + threadIdx.x;     // grid covers NB
    if (t < NB) y_out[t] = bias[0];
    if (t < NF) w_out[t] = __logf(1.0f + __expf(theta[t]));
}

// Main: lane=(row_lane, feature_lane). 16 features/block, params in LDS
// (read per h-step, amortized over RJ=8 rows of accumulators in VGPRs).
// x reads / Z writes are full-64B-line coalesced. y via shfl(16) + atomic.
__global__ __launch_bounds__(256)
void nul_main(const float* __restrict__ x,
              const float* __restrict__ W1, const float* __restrict__ b1,
              const float* __restrict__ W2, const float* __restrict__ b2,
              const float* __restrict__ W3, const float* __restrict__ b3,
              const float* __restrict__ theta,
              float* __restrict__ y_out, float* __restrict__ z_out) {
    // pads chosen so 16 distinct feature addresses land on >=16 banks
    // (worst case 2-way aliasing = free on gfx950, m136)
    __shared__ __align__(16) float sW1[FG][17];
    __shared__ __align__(16) float sB1[FG][17];
    __shared__ __align__(16) float sW2[FG][132];   // 132*4B = 33*16B: float4-aligned rows
    __shared__ __align__(16) float sB2[FG][12];
    __shared__ __align__(16) float sW3[FG][12];
    __shared__ float sB3[FG];
    __shared__ float sWv[FG];

    const int tid  = threadIdx.x;
    const int f0   = blockIdx.y * FG;
    const int row0 = blockIdx.x * ROWS_PER_BLOCK;

    // ---- cooperative param staging (once per block) ----
    {
        const int f = tid >> 4, h = tid & 15;          // 256 threads = 16f x 16h
        sW1[f][h] = W1[(f0 + f) * H1 + h];
        sB1[f][h] = b1[(f0 + f) * H1 + h];
    }
    {
        const int e = tid * 8;                          // 2048 floats of W2
        const int ff = e >> 7, c = e & 127;
        const float4* p = reinterpret_cast<const float4*>(W2 + (f0 + ff) * (H1 * H2) + c);
        float4 v0 = p[0], v1 = p[1];
        float* d = &sW2[ff][c];
        d[0] = v0.x; d[1] = v0.y; d[2] = v0.z; d[3] = v0.w;
        d[4] = v1.x; d[5] = v1.y; d[6] = v1.z; d[7] = v1.w;
    }
    if (tid < FG * H2) {
        const int f = tid >> 3, k = tid & 7;
        sB2[f][k] = b2[(f0 + f) * H2 + k];
        sW3[f][k] = W3[(f0 + f) * H2 + k];
    }
    if (tid < FG) {
        sB3[tid] = b3[f0 + tid];
        sWv[tid] = __logf(1.0f + __expf(theta[f0 + tid]));
    }
    __syncthreads();

    const int fl = tid & 15;        // feature lane
    const int rl = tid >> 4;        // row lane (0..15 across block, 4/wave)
    const int f  = f0 + fl;

    // x loads: per wave, 4 row-groups x 16 features = 4 fully-used 64B lines
    float xv[RJ];
    #pragma unroll
    for (int j = 0; j < RJ; ++j)
        xv[j] = x[(row0 + rl + 16 * j) * NF + f];

    float acc[RJ][H2];
    {
        const float4 ba = *reinterpret_cast<const float4*>(&sB2[fl][0]);
        const float4 bb = *reinterpret_cast<const float4*>(&sB2[fl][4]);
        #pragma unroll
        for (int j = 0; j < RJ; ++j) {
            acc[j][0] = ba.x; acc[j][1] = ba.y; acc[j][2] = ba.z; acc[j][3] = ba.w;
            acc[j][4] = bb.x; acc[j][5] = bb.y; acc[j][6] = bb.z; acc[j][7] = bb.w;
        }
    }

    #pragma unroll
    for (int h = 0; h < H1; ++h) {
        const float  w1h = sW1[fl][h];
        const float  b1h = sB1[fl][h];
        const float4 wa  = *reinterpret_cast<const float4*>(&sW2[fl][h * 8]);
        const float4 wb  = *reinterpret_cast<const float4*>(&sW2[fl][h * 8 + 4]);
        #pragma unroll
        for (int j = 0; j < RJ; ++j) {
            const float h1 = elu_f(fmaf(xv[j], w1h, b1h));
            acc[j][0] = fmaf(h1, wa.x, acc[j][0]);
            acc[j][1] = fmaf(h1, wa.y, acc[j][1]);
            acc[j][2] = fmaf(h1, wa.z, acc[j][2]);
            acc[j][3] = fmaf(h1, wa.w, acc[j][3]);
            acc[j][4] = fmaf(h1, wb.x, acc[j][4]);
            acc[j][5] = fmaf(h1, wb.y, acc[j][5]);
            acc[j][6] = fmaf(h1, wb.z, acc[j][6]);
            acc[j][7] = fmaf(h1, wb.w, acc[j][7]);
        }
    }

    const float4 w3a = *reinterpret_cast<const float4*>(&sW3[fl][0]);
    const float4 w3b = *reinterpret_cast<const float4*>(&sW3[fl][4]);
    const float  b3v = sB3[fl];
    const float  wv  = sWv[fl];

    #pragma unroll
    for (int j = 0; j < RJ; ++j) {
        float z = b3v;
        z = fmaf(elu_f(acc[j][0]), w3a.x, z);
        z = fmaf(elu_f(acc[j][1]), w3a.y, z);
        z = fmaf(elu_f(acc[j][2]), w3a.z, z);
        z = fmaf(elu_f(acc[j][3]), w3a.w, z);
        z = fmaf(elu_f(acc[j][4]), w3b.x, z);
        z = fmaf(elu_f(acc[j][5]), w3b.y, z);
        z = fmaf(elu_f(acc[j][6]), w3b.z, z);
        z = fmaf(elu_f(acc[j][7]), w3b.w, z);

        const int row = row0 + rl + 16 * j;
        z_out[row * NF + f] = z;                 // full-line coalesced per wave

        float p = wv * z;                        // y partial over 16 features
        p += __shfl_xor(p, 1, 16);
        p += __shfl_xor(p, 2, 16);
        p += __shfl_xor(p, 4, 16);
        p += __shfl_xor(p, 8, 16);
        if (fl == 0) unsafeAtomicAdd(&y_out[row], p);
    }
}

extern "C" void kernel_launch(void* const* d_in, const int* in_sizes, int n_in,
                              void* d_out, int out_size, void* d_ws, size_t ws_size,
                              hipStream_t stream) {
    const float* x     = (const float*)d_in[0];
    const float* W1    = (const float*)d_in[1];
    const float* b1    = (const float*)d_in[2];
    const float* W2    = (const float*)d_in[3];
    const float* b2    = (const float*)d_in[4];
    const float* W3    = (const float*)d_in[5];
    const float* b3    = (const float*)d_in[6];
    const float* theta = (const float*)d_in[7];
    const float* bias  = (const float*)d_in[8];

    float* y_out = (float*)d_out;                  // [32768]
    float* w_out = y_out + NB;                     // [256]
    float* z_out = w_out + NF;                     // [32768*256]

    nul_init<<<NB / 256, 256, 0, stream>>>(theta, bias, y_out, w_out);

    dim3 grid(NB / ROWS_PER_BLOCK, NF / FG);       // (256, 16)
    nul_main<<<grid, 256, 0, stream>>>(
        x, W1, b1, W2, b2, W3, b3, theta, y_out, z_out);
}